// Round 20
// baseline (42.911 us; speedup 1.0000x reference)
//
#include <hip/hip_runtime.h>
#include <hip/hip_bf16.h>

// Masked SDPA, B=16, NQ=2048, NKV=2048, D=64, f32 in/out, bf16 MFMA compute.
// R20: QBLK=64 — halve load-instructions per unit work. R19's null (2x TLP,
// balanced, L2-affine -> zero change) proves the floor is a per-CU shared
// throughput resource; audit: every structure R7-R19 issued 16 vector-memory
// loads per 32q x 64kv tile through the CU's single TA/L1 port (~2048 cy per
// 8-wave iter-round, invariant under TLP). Fix: wave owns 64 q-rows (two 32-q
// B-fragments): SAME 16 loads per tile now feed 32 MFMA -> port demand per
// work halves; worst-case iters 16 -> 8. Q-group pair also gives 4
// independent PV chains/body (supersedes R13's A/B split). Single-kf
// prefetch (R18 pattern), amdgpu_waves_per_eu(2,2) for ~240 VGPR (R18-
// verified), 4-way kv-quarter merge in padded LDS (R10-verified epilogue).

typedef __attribute__((ext_vector_type(8))) short short8;
typedef __attribute__((ext_vector_type(4))) short short4v;
typedef __attribute__((ext_vector_type(4))) float float4v;
typedef __attribute__((ext_vector_type(16))) float f32x16;

#define BATCH 16
#define NQ 2048
#define NKV 2048
#define DH 64
#define KVB 64
#define NTILES (NKV / KVB)          // 32
#define TILE_ELEMS (KVB * DH)       // 4096 bf16 = 8 KB per tile per array
#define NEG_INF -1e20f
// (1/sqrt(64)) * log2(e)
#define SCALE_LOG2 0.180336880111120f
#define MPAD 66                     // merge row pad (floats)

__device__ __forceinline__ short f2bf(float x) {
    union { float f; unsigned u; } v; v.f = x;
    unsigned r = (v.u + 0x7fffu + ((v.u >> 16) & 1u)) >> 16;
    return (short)r;
}

__device__ __forceinline__ short8 cvt8(float4v a, float4v b) {
    short8 r;
    r[0] = f2bf(a[0]); r[1] = f2bf(a[1]); r[2] = f2bf(a[2]); r[3] = f2bf(a[3]);
    r[4] = f2bf(b[0]); r[5] = f2bf(b[1]); r[6] = f2bf(b[2]); r[7] = f2bf(b[3]);
    return r;
}

__device__ __forceinline__ float fexp2(float x) {
    float r; asm("v_exp_f32 %0, %1" : "=v"(r) : "v"(x)); return r;
}

// ---- prep: f32 -> bf16 fragment-sequential layouts (unchanged) -------------
__global__ __launch_bounds__(256) void prep_kernel(
    const float* __restrict__ K, const float* __restrict__ V,
    const int* __restrict__ valid_lens,
    short* __restrict__ Kf, short* __restrict__ Vf)
{
    const int b    = blockIdx.x >> 5;
    const int tile = blockIdx.x & 31;
    const int vlen = valid_lens[b];
    const int nkv  = (vlen == 0) ? NKV : vlen;
    if (tile * KVB >= nkv) return;          // never read by attn

    const int tid = threadIdx.x;
    const int ln  = tid & 63;
    const int l31 = ln & 31;
    const int hi8 = (ln >> 5) * 8;
    const size_t gbase = ((size_t)b * NKV + (size_t)tile * KVB) * DH;
    short* kt = Kf + (((size_t)b * NTILES + tile) * TILE_ELEMS);
    short* vt = Vf + (((size_t)b * NTILES + tile) * TILE_ELEMS);

#pragma unroll
    for (int s = 0; s < 2; ++s) {           // K frags: slots s*256+tid
        const int kk = tid >> 6;            // 0..3
        const int kv = s * 32 + l31;
        const int d  = kk * 16 + hi8;
        const float* p = K + gbase + (size_t)kv * DH + d;
        *reinterpret_cast<short8*>(kt + (s * 256 + tid) * 8) =
            cvt8(*reinterpret_cast<const float4v*>(p),
                 *reinterpret_cast<const float4v*>(p + 4));
    }
    {   // V: 4x4 float4 transpose -> short4 writes into frag-sequential layout
        const int kv0 = (tid >> 4) << 2;    // 0..60 step 4
        const int d0  = (tid & 15) << 2;    // 0..60 step 4
        const float* p = V + gbase + (size_t)kv0 * DH + d0;
        float4v r0 = *reinterpret_cast<const float4v*>(p);
        float4v r1 = *reinterpret_cast<const float4v*>(p + DH);
        float4v r2 = *reinterpret_cast<const float4v*>(p + 2 * DH);
        float4v r3 = *reinterpret_cast<const float4v*>(p + 3 * DH);
        const int ks  = kv0 >> 4;
        const int hiv = (kv0 >> 3) & 1;
        const int j0  = kv0 & 7;            // 0 or 4
#pragma unroll
        for (int k = 0; k < 4; ++k) {
            const int d    = d0 + k;
            const int lanev = (d & 31) + 32 * hiv;
            short4v w;
            w[0] = f2bf(r0[k]); w[1] = f2bf(r1[k]);
            w[2] = f2bf(r2[k]); w[3] = f2bf(r3[k]);
            *reinterpret_cast<short4v*>(
                vt + (((d >> 5) * 4 + ks) * 64 + lanev) * 8 + j0) = w;
        }
    }
}

// ------ attn: 8 waves = 2 qsub(64 q-rows) x 4 KV-quarters, QBLK=64 ----------
__global__
__attribute__((amdgpu_flat_work_group_size(512, 512), amdgpu_waves_per_eu(2, 2)))
void attn_fwd_kernel(
    const float* __restrict__ Q,
    const short* __restrict__ Kf,
    const short* __restrict__ Vf,
    const int* __restrict__ vl,
    float* __restrict__ O)
{
    __shared__ float  mrg[2][4][64][MPAD]; // [qsub][kvq][q][d] (~135 KB)
    __shared__ float2 mlb[2][4][64];

    const int tid  = threadIdx.x;
    const int wave = tid >> 6;
    const int lane = tid & 63;
    const int l31  = lane & 31;
    const int hi   = lane >> 5;
    const int qsub = wave >> 2;            // 0..1
    const int kvq  = wave & 3;             // KV quarter

    const int b  = blockIdx.x & 15;        // 2 batches per XCD (L2-affine)
    const int qt = blockIdx.x >> 4;        // 0..15
    const int qbase = qt * 128 + qsub * 64;

    const int vlen  = vl[b];
    const int nkv   = (vlen == 0) ? NKV : vlen;
    const int tiles = (nkv + KVB - 1) >> 6;
    const int nh    = (tiles - kvq + 3) >> 2;  // my quarter (stride 4)

    // Q B-fragments, 2 q-groups of 32: lane col q=qg*32+l31, k d=kk*16+hi*8+j
    short8 qfrag[2][4];
#pragma unroll
    for (int qg = 0; qg < 2; ++qg) {
        const float* Qb = Q + ((size_t)b * NQ + qbase + qg * 32 + l31) * DH;
#pragma unroll
        for (int kk = 0; kk < 4; ++kk) {
            const float* p = Qb + kk * 16 + hi * 8;
            float4v a = *reinterpret_cast<const float4v*>(p);
            float4v c = *reinterpret_cast<const float4v*>(p + 4);
#pragma unroll
            for (int j = 0; j < 4; ++j) { a[j] *= SCALE_LOG2; c[j] *= SCALE_LOG2; }
            qfrag[qg][kk] = cvt8(a, c);
        }
    }

    const short* Kfb = Kf + (size_t)b * NTILES * TILE_ELEMS + lane * 8;
    const short* Vfb = Vf + (size_t)b * NTILES * TILE_ELEMS + lane * 8;

    short8 kf[8];                          // single K buffer (R18 pattern)
    auto load_k = [&](int tile) {
        const short* p = Kfb + (size_t)tile * TILE_ELEMS;
#pragma unroll
        for (int i = 0; i < 8; ++i)
            kf[i] = *reinterpret_cast<const short8*>(p + i * 512);
    };

    f32x16 acc[2][2];                      // [qg][t]: 4 independent PV chains
#pragma unroll
    for (int qg = 0; qg < 2; ++qg)
#pragma unroll
        for (int t = 0; t < 2; ++t)
#pragma unroll
            for (int r = 0; r < 16; ++r) acc[qg][t][r] = 0.f;
    float m[2]    = {-INFINITY, -INFINITY};
    float lsum[2] = {0.f, 0.f};

    if (nh > 0) load_k(kvq);

    for (int it = 0; it < nh; ++it) {
        const int tile = 4 * it + kvq;

        short8 vfr[8];                     // V fragments, shared by both qg
        {
            const short* p = Vfb + (size_t)tile * TILE_ELEMS;
#pragma unroll
            for (int i = 0; i < 8; ++i)
                vfr[i] = *reinterpret_cast<const short8*>(p + i * 512);
        }

        // ---- S^T = K Q^T for both q-groups (K shared in-register) ----
        f32x16 acs[2][2];                  // [qg][s]
#pragma unroll
        for (int qg = 0; qg < 2; ++qg)
#pragma unroll
            for (int s = 0; s < 2; ++s)
#pragma unroll
                for (int r = 0; r < 16; ++r) acs[qg][s][r] = 0.f;
        __builtin_amdgcn_s_setprio(1);
#pragma unroll
        for (int qg = 0; qg < 2; ++qg)
#pragma unroll
            for (int s = 0; s < 2; ++s)
#pragma unroll
                for (int kk = 0; kk < 4; ++kk)
                    acs[qg][s] = __builtin_amdgcn_mfma_f32_32x32x16_bf16(
                        kf[s * 4 + kk], qfrag[qg][kk], acs[qg][s], 0, 0, 0);
        __builtin_amdgcn_s_setprio(0);

        if (it + 1 < nh) load_k(4 * (it + 1) + kvq);  // kf dead: refill early

        // ---- mask (kv-dependent only; same for both qg) ----
        if (vlen < (tile + 1) * KVB) {
            const int kvb0 = tile * KVB + 4 * hi;
#pragma unroll
            for (int qg = 0; qg < 2; ++qg)
#pragma unroll
                for (int s = 0; s < 2; ++s) {
                    const int vlim = vlen - (kvb0 + s * 32);
#pragma unroll
                    for (int r = 0; r < 16; ++r) {
                        const int rc = (r & 3) + 8 * (r >> 2);
                        acs[qg][s][r] = (rc < vlim) ? acs[qg][s][r] : NEG_INF;
                    }
                }
        }

        // ---- per-q-group softmax + PV ----
#pragma unroll
        for (int qg = 0; qg < 2; ++qg) {
            // row max: depth-5 tree + 1 shuffle
            float mx[8];
#pragma unroll
            for (int r = 0; r < 8; ++r)
                mx[r] = fmaxf(fmaxf(acs[qg][0][r], acs[qg][0][r + 8]),
                              fmaxf(acs[qg][1][r], acs[qg][1][r + 8]));
#pragma unroll
            for (int d = 4; d; d >>= 1)
#pragma unroll
                for (int r = 0; r < d; ++r) mx[r] = fmaxf(mx[r], mx[r + d]);
            float xv = mx[0];
            xv = fmaxf(xv, __shfl_xor(xv, 32, 64));

            // T13 defer-max
            float mn = m[qg];
            if (!__all(xv <= m[qg] + 8.f)) {
                mn = fmaxf(m[qg], xv);
                const float alpha = fexp2(m[qg] - mn);   // m=-inf first -> 0
                m[qg] = mn;
                lsum[qg] *= alpha;
#pragma unroll
                for (int r = 0; r < 16; ++r) {
                    const int rc = (r & 3) + 8 * (r >> 2);
                    const float ar = __shfl(alpha, rc + 4 * hi, 64);
                    acc[qg][0][r] *= ar; acc[qg][1][r] *= ar;
                }
            }

            // P = 2^(s - mn); sum tree + 1 shuffle
#pragma unroll
            for (int s = 0; s < 2; ++s)
#pragma unroll
                for (int r = 0; r < 16; ++r)
                    acs[qg][s][r] = fexp2(acs[qg][s][r] - mn);
            float sm[8];
#pragma unroll
            for (int r = 0; r < 8; ++r)
                sm[r] = (acs[qg][0][r] + acs[qg][0][r + 8]) +
                        (acs[qg][1][r] + acs[qg][1][r + 8]);
#pragma unroll
            for (int d = 4; d; d >>= 1)
#pragma unroll
                for (int r = 0; r < d; ++r) sm[r] += sm[r + d];
            float rs = sm[0];
            rs += __shfl_xor(rs, 32, 64);
            lsum[qg] += rs;

            // P -> bf16 packs (16 cvt_pk)
            unsigned pk[2][4][2];
#pragma unroll
            for (int s = 0; s < 2; ++s)
#pragma unroll
                for (int be = 0; be < 4; ++be)
#pragma unroll
                    for (int c = 0; c < 2; ++c)
                        asm("v_cvt_pk_bf16_f32 %0, %1, %2"
                            : "=v"(pk[s][be][c])
                            : "v"(acs[qg][s][4 * be + 2 * c]),
                              "v"(acs[qg][s][4 * be + 2 * c + 1]));

            // O(qg) += P V: permlane32_swap builds A-frags; V shared
            __builtin_amdgcn_s_setprio(1);
#pragma unroll
            for (int ks = 0; ks < 4; ++ks) {
                const int s = ks >> 1, g = ks & 1;
                unsigned w0 = pk[s][2 * g][0], w2 = pk[s][2 * g + 1][0];
                unsigned w1 = pk[s][2 * g][1], w3 = pk[s][2 * g + 1][1];
                asm("v_permlane32_swap_b32 %0, %1" : "+v"(w0), "+v"(w2));
                asm("v_permlane32_swap_b32 %0, %1" : "+v"(w1), "+v"(w3));
                union { unsigned u[4]; short8 s8; } pf;
                pf.u[0] = w0; pf.u[1] = w1; pf.u[2] = w2; pf.u[3] = w3;
#pragma unroll
                for (int t = 0; t < 2; ++t)
                    acc[qg][t] = __builtin_amdgcn_mfma_f32_32x32x16_bf16(
                        pf.s8, vfr[t * 4 + ks], acc[qg][t], 0, 0, 0);
            }
            __builtin_amdgcn_s_setprio(0);
        }
    }

    // ---- 4-way merge across KV quarters (shuffle-free) ----
#pragma unroll
    for (int qg = 0; qg < 2; ++qg)
#pragma unroll
        for (int t = 0; t < 2; ++t)
#pragma unroll
            for (int r = 0; r < 16; ++r) {
                const int rc = (r & 3) + 8 * (r >> 2);
                mrg[qsub][kvq][qg * 32 + rc + 4 * hi][t * 32 + l31] =
                    acc[qg][t][r];
            }
    if (hi == 0) {
        mlb[qsub][kvq][l31]      = float2{m[0], lsum[0]};
        mlb[qsub][kvq][32 + l31] = float2{m[1], lsum[1]};
    }
    __syncthreads();

    // epilogue: thread -> (qsubo, 1 q-row, 16 d-cols)
    {
        const int qsubo = wave >> 2;
        const int qq = (wave & 3) * 16 + (lane >> 2);   // 0..63
        const int dg = (lane & 3) * 16;                 // 0,16,32,48
        float mi[4], li[4];
#pragma unroll
        for (int ii = 0; ii < 4; ++ii) {
            const float2 c = mlb[qsubo][ii][qq];
            mi[ii] = c.x; li[ii] = c.y;
        }
        const float M = fmaxf(fmaxf(mi[0], mi[1]), fmaxf(mi[2], mi[3]));
        float wgt[4], L = 0.f;
#pragma unroll
        for (int ii = 0; ii < 4; ++ii) {
            wgt[ii] = fexp2(mi[ii] - M);       // mi=-inf -> 0
            L += li[ii] * wgt[ii];
        }
        const float Linv = 1.f / L;
#pragma unroll
        for (int ii = 0; ii < 4; ++ii) wgt[ii] *= Linv;

        float4v o[4];
#pragma unroll
        for (int j = 0; j < 4; ++j) o[j] = float4v{0.f, 0.f, 0.f, 0.f};
#pragma unroll
        for (int ii = 0; ii < 4; ++ii) {
            const float* src = &mrg[qsubo][ii][qq][dg];
#pragma unroll
            for (int j = 0; j < 4; ++j) {
                float4v a = *reinterpret_cast<const float4v*>(src + 4 * j);
#pragma unroll
                for (int k = 0; k < 4; ++k) o[j][k] += a[k] * wgt[ii];
            }
        }
        float* Ob = O + ((size_t)b * NQ + qt * 128 + qsubo * 64 + qq) * DH + dg;
#pragma unroll
        for (int j = 0; j < 4; ++j)
            *reinterpret_cast<float4v*>(Ob + 4 * j) = o[j];
    }
}

extern "C" void kernel_launch(void* const* d_in, const int* in_sizes, int n_in,
                              void* d_out, int out_size, void* d_ws, size_t ws_size,
                              hipStream_t stream) {
    const float* Q = (const float*)d_in[0];
    const float* K = (const float*)d_in[1];
    const float* V = (const float*)d_in[2];
    const int* vl  = (const int*)d_in[3];
    float* Out     = (float*)d_out;

    short* Kws = (short*)d_ws;
    short* Vws = Kws + (size_t)BATCH * NTILES * TILE_ELEMS;

    prep_kernel<<<dim3(BATCH * NTILES), dim3(256), 0, stream>>>(K, V, vl, Kws, Vws);
    attn_fwd_kernel<<<dim3(256), dim3(512), 0, stream>>>(Q, Kws, Vws, vl, Out);
}

// Round 21
// 38.299 us; speedup vs baseline: 1.1204x; 1.1204x over previous
//
#include <hip/hip_runtime.h>
#include <hip/hip_bf16.h>

// Masked SDPA, B=16, NQ=2048, NKV=2048, D=64, f32 in/out, bf16 MFMA compute.
// R21 = R13 (best, 35.1us) + ONE change: lockstep barriers in the main loop.
// Theory: R13's barrier-free waves drift across iterations -> the 4 qsub
// waves (which issue byte-identical K/V fragment addresses) stop sharing L1;
// per-CU live set 8x16KB=128KB >> 32KB L1 -> every load served by L2
// (~2300cy/iter-round at ~56B/cy/CU), explaining the ~4500cy/iter invariant
// that TLP (R19 null) and load-halving (R20) couldn't move. One s_barrier
// before each body keeps waves in phase: L1 window = 2 tiles x 16KB = L1
// capacity; L2 traffic per iter-round drops 4x. All waves loop to the same
// n0 with guarded bodies -> uniform barrier counts (no divergence hazard).
// Body otherwise byte-identical to R13: chain-split A/B accumulators,
// reg-direct fragment loads, swapped 32x32 QK^T, in-reg P (cvt_pk +
// permlane32_swap), T13 defer-max, raw v_exp_f32, LDS merge epilogue.

typedef __attribute__((ext_vector_type(8))) short short8;
typedef __attribute__((ext_vector_type(4))) short short4v;
typedef __attribute__((ext_vector_type(4))) float float4v;
typedef __attribute__((ext_vector_type(16))) float f32x16;

#define BATCH 16
#define NQ 2048
#define NKV 2048
#define DH 64
#define KVB 64
#define NTILES (NKV / KVB)          // 32
#define TILE_ELEMS (KVB * DH)       // 4096 bf16 = 8 KB per tile per array
#define NEG_INF -1e20f
// (1/sqrt(64)) * log2(e)
#define SCALE_LOG2 0.180336880111120f

__device__ __forceinline__ short f2bf(float x) {
    union { float f; unsigned u; } v; v.f = x;
    unsigned r = (v.u + 0x7fffu + ((v.u >> 16) & 1u)) >> 16;
    return (short)r;
}

__device__ __forceinline__ short8 cvt8(float4v a, float4v b) {
    short8 r;
    r[0] = f2bf(a[0]); r[1] = f2bf(a[1]); r[2] = f2bf(a[2]); r[3] = f2bf(a[3]);
    r[4] = f2bf(b[0]); r[5] = f2bf(b[1]); r[6] = f2bf(b[2]); r[7] = f2bf(b[3]);
    return r;
}

__device__ __forceinline__ float fexp2(float x) {
    float r; asm("v_exp_f32 %0, %1" : "=v"(r) : "v"(x)); return r;
}

// ---- prep: f32 -> bf16 fragment-sequential layouts (unchanged) -------------
__global__ __launch_bounds__(256) void prep_kernel(
    const float* __restrict__ K, const float* __restrict__ V,
    const int* __restrict__ valid_lens,
    short* __restrict__ Kf, short* __restrict__ Vf)
{
    const int b    = blockIdx.x >> 5;
    const int tile = blockIdx.x & 31;
    const int vlen = valid_lens[b];
    const int nkv  = (vlen == 0) ? NKV : vlen;
    if (tile * KVB >= nkv) return;          // never read by attn

    const int tid = threadIdx.x;
    const int ln  = tid & 63;
    const int l31 = ln & 31;
    const int hi8 = (ln >> 5) * 8;
    const size_t gbase = ((size_t)b * NKV + (size_t)tile * KVB) * DH;
    short* kt = Kf + (((size_t)b * NTILES + tile) * TILE_ELEMS);
    short* vt = Vf + (((size_t)b * NTILES + tile) * TILE_ELEMS);

#pragma unroll
    for (int s = 0; s < 2; ++s) {           // K frags: slots s*256+tid
        const int kk = tid >> 6;            // 0..3
        const int kv = s * 32 + l31;
        const int d  = kk * 16 + hi8;
        const float* p = K + gbase + (size_t)kv * DH + d;
        *reinterpret_cast<short8*>(kt + (s * 256 + tid) * 8) =
            cvt8(*reinterpret_cast<const float4v*>(p),
                 *reinterpret_cast<const float4v*>(p + 4));
    }
    {   // V: 4x4 float4 transpose -> short4 writes into frag-sequential layout
        const int kv0 = (tid >> 4) << 2;    // 0..60 step 4
        const int d0  = (tid & 15) << 2;    // 0..60 step 4
        const float* p = V + gbase + (size_t)kv0 * DH + d0;
        float4v r0 = *reinterpret_cast<const float4v*>(p);
        float4v r1 = *reinterpret_cast<const float4v*>(p + DH);
        float4v r2 = *reinterpret_cast<const float4v*>(p + 2 * DH);
        float4v r3 = *reinterpret_cast<const float4v*>(p + 3 * DH);
        const int ks  = kv0 >> 4;
        const int hiv = (kv0 >> 3) & 1;
        const int j0  = kv0 & 7;            // 0 or 4
#pragma unroll
        for (int k = 0; k < 4; ++k) {
            const int d    = d0 + k;
            const int lanev = (d & 31) + 32 * hiv;
            short4v w;
            w[0] = f2bf(r0[k]); w[1] = f2bf(r1[k]);
            w[2] = f2bf(r2[k]); w[3] = f2bf(r3[k]);
            *reinterpret_cast<short4v*>(
                vt + (((d >> 5) * 4 + ks) * 64 + lanev) * 8 + j0) = w;
        }
    }
}

// ------------- attn: 8 waves = 4 qsub(32 q-rows) x 2 KV halves --------------
__global__ __launch_bounds__(512) void attn_fwd_kernel(
    const float* __restrict__ Q,
    const short* __restrict__ Kf,
    const short* __restrict__ Vf,
    const int* __restrict__ valid_lens,
    float* __restrict__ O)
{
    __shared__ float  mrg[4][2048];        // halves merge (32 KB)
    __shared__ float2 mlb[4][32];

    const int tid  = threadIdx.x;
    const int wave = tid >> 6;
    const int lane = tid & 63;
    const int l31  = lane & 31;
    const int hi   = lane >> 5;
    const int h    = wave >> 2;            // KV half
    const int qsub = wave & 3;             // q sub-tile (32 rows)

    const int b  = blockIdx.x & 15;        // batch's 16 blocks -> same XCD L2
    const int qt = blockIdx.x >> 4;
    const int qbase = qt * 128 + qsub * 32;

    const int vlen  = valid_lens[b];
    const int nkv   = (vlen == 0) ? NKV : vlen;
    const int tiles = (nkv + KVB - 1) / KVB;
    const int nh = (tiles + 1 - h) >> 1;   // my half's tiles (interleaved)
    const int n0 = (tiles + 1) >> 1;       // uniform loop bound (max of halves)

    // Q B-fragments (scale folded): lane col q=l31, k-elems d = kk*16+hi*8+j
    const float* Qb = Q + ((size_t)b * NQ + qbase + l31) * DH;
    short8 qfrag[4];
#pragma unroll
    for (int kk = 0; kk < 4; ++kk) {
        const float* p = Qb + kk * 16 + hi * 8;
        float4v a = *reinterpret_cast<const float4v*>(p);
        float4v c = *reinterpret_cast<const float4v*>(p + 4);
#pragma unroll
        for (int j = 0; j < 4; ++j) { a[j] *= SCALE_LOG2; c[j] *= SCALE_LOG2; }
        qfrag[kk] = cvt8(a, c);
    }

    const short* Kfb = Kf + (size_t)b * NTILES * TILE_ELEMS + lane * 8;
    const short* Vfb = Vf + (size_t)b * NTILES * TILE_ELEMS + lane * 8;

    auto load_k = [&](short8 (&kf)[8], int k) {   // k-th tile of my half
        const short* p = Kfb + (size_t)(2 * k + h) * TILE_ELEMS;
#pragma unroll
        for (int i = 0; i < 8; ++i)
            kf[i] = *reinterpret_cast<const short8*>(p + i * 512);
    };

    f32x16 acc_oA[2], acc_oB[2];
#pragma unroll
    for (int t = 0; t < 2; ++t)
#pragma unroll
        for (int r = 0; r < 16; ++r) { acc_oA[t][r] = 0.f; acc_oB[t][r] = 0.f; }
    float m = -INFINITY, lsum = 0.f;

    short8 kf0[8], kf1[8];

    auto body = [&](short8 (&kc)[8], short8 (&kn)[8], f32x16 (&am)[2], int it) {
        const int tile = 2 * it + h;

        short8 vfr[8];                     // body-local V fragments
        {
            const short* p = Vfb + (size_t)tile * TILE_ELEMS;
#pragma unroll
            for (int i = 0; i < 8; ++i)
                vfr[i] = *reinterpret_cast<const short8*>(p + i * 512);
        }

        // ---- S^T = K Q^T: lane owns q=l31, kv = 32s + (r&3)+8(r>>2)+4hi ----
        f32x16 acs[2];
#pragma unroll
        for (int s = 0; s < 2; ++s)
#pragma unroll
            for (int r = 0; r < 16; ++r) acs[s][r] = 0.f;
        __builtin_amdgcn_s_setprio(1);
#pragma unroll
        for (int s = 0; s < 2; ++s)
#pragma unroll
            for (int kk = 0; kk < 4; ++kk)
                acs[s] = __builtin_amdgcn_mfma_f32_32x32x16_bf16(
                    kc[s * 4 + kk], qfrag[kk], acs[s], 0, 0, 0);
        __builtin_amdgcn_s_setprio(0);

        if (it + 1 < nh) load_k(kn, it + 1);  // prefetch next K of my half

        // ---- mask, skipped for fully-valid tiles (wave-uniform) ----
        if (vlen < (tile + 1) * KVB) {
            const int kvb0 = tile * KVB + 4 * hi;
#pragma unroll
            for (int s = 0; s < 2; ++s) {
                const int vlim = vlen - (kvb0 + s * 32);
#pragma unroll
                for (int r = 0; r < 16; ++r) {
                    const int rc = (r & 3) + 8 * (r >> 2);
                    acs[s][r] = (rc < vlim) ? acs[s][r] : NEG_INF;
                }
            }
        }

        // ---- row max: depth-5 tree + 1 shuffle ----
        float mx[8];
#pragma unroll
        for (int r = 0; r < 8; ++r)
            mx[r] = fmaxf(fmaxf(acs[0][r], acs[0][r + 8]),
                          fmaxf(acs[1][r], acs[1][r + 8]));
#pragma unroll
        for (int d = 4; d; d >>= 1)
#pragma unroll
            for (int r = 0; r < d; ++r) mx[r] = fmaxf(mx[r], mx[r + d]);
        float xv = mx[0];
        xv = fmaxf(xv, __shfl_xor(xv, 32, 64));

        // ---- T13 defer-max (rescale BOTH accumulator sets; rare) ----
        float mn = m;
        if (!__all(xv <= m + 8.f)) {
            mn = fmaxf(m, xv);
            const float alpha = fexp2(m - mn);   // m=-inf first -> 0
            m = mn;
            lsum *= alpha;
#pragma unroll
            for (int r = 0; r < 16; ++r) {
                const int rc = (r & 3) + 8 * (r >> 2);
                const float ar = __shfl(alpha, rc + 4 * hi, 64);
                acc_oA[0][r] *= ar; acc_oA[1][r] *= ar;
                acc_oB[0][r] *= ar; acc_oB[1][r] *= ar;
            }
        }

        // ---- P = 2^(s - mn); sum as tree + 1 shuffle ----
#pragma unroll
        for (int s = 0; s < 2; ++s)
#pragma unroll
            for (int r = 0; r < 16; ++r) acs[s][r] = fexp2(acs[s][r] - mn);
        float sm[8];
#pragma unroll
        for (int r = 0; r < 8; ++r)
            sm[r] = (acs[0][r] + acs[0][r + 8]) + (acs[1][r] + acs[1][r + 8]);
#pragma unroll
        for (int d = 4; d; d >>= 1)
#pragma unroll
            for (int r = 0; r < d; ++r) sm[r] += sm[r + d];
        float rs = sm[0];
        rs += __shfl_xor(rs, 32, 64);
        lsum += rs;

        // ---- P -> bf16 packs (16 cvt_pk) ----
        unsigned pk[2][4][2];
#pragma unroll
        for (int s = 0; s < 2; ++s)
#pragma unroll
            for (int be = 0; be < 4; ++be)
#pragma unroll
                for (int c = 0; c < 2; ++c)
                    asm("v_cvt_pk_bf16_f32 %0, %1, %2"
                        : "=v"(pk[s][be][c])
                        : "v"(acs[s][4 * be + 2 * c]),
                          "v"(acs[s][4 * be + 2 * c + 1]));

        // ---- O(me) += P V: 8 permlane32_swap build A-frags in-register ----
        __builtin_amdgcn_s_setprio(1);
#pragma unroll
        for (int ks = 0; ks < 4; ++ks) {
            const int s = ks >> 1, g = ks & 1;
            unsigned w0 = pk[s][2 * g][0], w2 = pk[s][2 * g + 1][0];
            unsigned w1 = pk[s][2 * g][1], w3 = pk[s][2 * g + 1][1];
            asm("v_permlane32_swap_b32 %0, %1" : "+v"(w0), "+v"(w2));
            asm("v_permlane32_swap_b32 %0, %1" : "+v"(w1), "+v"(w3));
            union { unsigned u[4]; short8 s8; } pf;
            pf.u[0] = w0; pf.u[1] = w1; pf.u[2] = w2; pf.u[3] = w3;
#pragma unroll
            for (int t = 0; t < 2; ++t)
                am[t] = __builtin_amdgcn_mfma_f32_32x32x16_bf16(
                    pf.s8, vfr[t * 4 + ks], am[t], 0, 0, 0);
        }
        __builtin_amdgcn_s_setprio(0);
    };

    // ---- lockstep main loop: one barrier per body, uniform count n0 ----
    if (nh > 0) load_k(kf0, 0);
    int it = 0;
    for (; it + 1 < n0; it += 2) {
        __builtin_amdgcn_s_barrier();      // phase-align the 8 waves
        if (it < nh) body(kf0, kf1, acc_oA, it);
        __builtin_amdgcn_s_barrier();
        if (it + 1 < nh) body(kf1, kf0, acc_oB, it + 1);
    }
    if (it < n0) {
        __builtin_amdgcn_s_barrier();
        if (it < nh) body(kf0, kf1, acc_oA, it);
    }

    // combine the two chains (same scale)
#pragma unroll
    for (int t = 0; t < 2; ++t)
#pragma unroll
        for (int r = 0; r < 16; ++r) acc_oA[t][r] += acc_oB[t][r];

    // ---- merge the two KV halves; h==0 writes output ----
    if (h == 1) {
#pragma unroll
        for (int t = 0; t < 2; ++t)
#pragma unroll
            for (int r = 0; r < 16; ++r)
                mrg[qsub][(t * 16 + r) * 64 + lane] = acc_oA[t][r];
        if (lane < 32) mlb[qsub][lane] = float2{m, lsum};
    }
    __syncthreads();
    if (h == 0) {
        const float2 o1 = mlb[qsub][l31];
        const float m1 = o1.x, l1 = o1.y;
        const float M  = (l1 > 0.f) ? fmaxf(m, m1) : m;
        const float w0 = fexp2(m - M);
        const float w1 = (l1 > 0.f) ? fexp2(m1 - M) : 0.f;
        const float L  = lsum * w0 + l1 * w1;
        const float a0 = w0 / L, a1 = w1 / L;
        float* Ob = O + ((size_t)b * NQ + qbase) * DH;
#pragma unroll
        for (int r = 0; r < 16; ++r) {
            const int rc = (r & 3) + 8 * (r >> 2);
            const float a0r = __shfl(a0, rc + 4 * hi, 64);
            const float a1r = __shfl(a1, rc + 4 * hi, 64);
#pragma unroll
            for (int t = 0; t < 2; ++t) {
                const float oh = mrg[qsub][(t * 16 + r) * 64 + lane];
                Ob[(size_t)(rc + 4 * hi) * DH + t * 32 + l31] =
                    acc_oA[t][r] * a0r + oh * a1r;
            }
        }
    }
}

extern "C" void kernel_launch(void* const* d_in, const int* in_sizes, int n_in,
                              void* d_out, int out_size, void* d_ws, size_t ws_size,
                              hipStream_t stream) {
    const float* Q = (const float*)d_in[0];
    const float* K = (const float*)d_in[1];
    const float* V = (const float*)d_in[2];
    const int* vl  = (const int*)d_in[3];
    float* Out     = (float*)d_out;

    short* Kws = (short*)d_ws;
    short* Vws = Kws + (size_t)BATCH * NTILES * TILE_ELEMS;

    prep_kernel<<<dim3(BATCH * NTILES), dim3(256), 0, stream>>>(K, V, vl, Kws, Vws);
    attn_fwd_kernel<<<dim3(BATCH * (NQ / 128)), dim3(512), 0, stream>>>(
        Q, Kws, Vws, vl, Out);
}